// Round 1
// 347.064 us; speedup vs baseline: 1.1900x; 1.1900x over previous
//
#include <hip/hip_runtime.h>
#include <math.h>

#define TT 8192
#define BB 256
#define EE 8
#define KK 15
#define PI_F  3.14159265358979323846f
#define TPI_F 6.28318530717958647692f

// d_out flat layout (reference tuple order)
#define OFF_OUT 0
#define OFF_LAT (BB*TT)
#define OFF_SIG (OFF_LAT + BB*EE*TT)
#define OFF_P   (OFF_SIG + BB*EE*TT)
#define OFF_F   (OFF_P + BB*EE)
#define OFF_A   (OFF_F + BB*EE)
#define OFF_B0  (OFF_A + BB*EE)

#define TILE_C 1024

// swizzle for fft LDS only
#define SWZ(i) ((i) + ((i) >> 5))

// =====================================================================
// Kernel A: composed dilated conv, FULL-ROW polyphase LDS layout.
// One block per (e, b): 2048 blocks x 512 threads, dynamic LDS.
// sxp[ph*Lp + n] = x[-14d + ph + n*d]; a thread's 29-tap dilated window
// is CONTIGUOUS -> 8x ds_read_b128. Boundary (row edges only): clipped-h
// correction values hbF/hbL computed once per block.
// LDS worst case (e=7): 128*92 + 28*128 + 96 = 15456 floats = 61824 B
// -> 2 blocks/CU resident, 16 waves/CU.
// =====================================================================
__global__ __launch_bounds__(512) void conv_stack_kernel(
    const float* __restrict__ x, const float* __restrict__ W1,
    const float* __restrict__ b1, const float* __restrict__ W2,
    const float* __restrict__ b2, float* __restrict__ latent)
{
  extern __shared__ float smem[];
  const int e = blockIdx.x, b = blockIdx.y;
  const int d  = 1 << e;
  const int M  = TT >> e;                               // outputs per phase
  const int Lp = (M <= 64) ? 92 : ((((M + 47) >> 5) << 5) + 12);  // >= M+28
  float* sxp = smem;                                    // d*Lp floats
  float* hbF = smem + d * Lp;                           // [2][7d] first-edge h~
  float* hbL = hbF + 14 * d;                            // [2][7d] last-edge h~
  float* sW  = hbL + 14 * d;                            // 96 floats
  const int tid = threadIdx.x;
  const float* xr = x + b * TT;

  // ---- stage full x row into polyphase layout (coalesced over i)
  const int nstage = TT + 28 * d;
  for (int i = tid; i < nstage; i += 512) {
    int t  = i - 14 * d;
    int ph = i & (d - 1);
    int n  = i >> e;
    sxp[ph * Lp + n] = (t >= 0 && t < TT) ? xr[t] : 0.0f;
  }

  // ---- weights: composed 29-tap + raw
  if (tid < 29) {
    float acc = 0.0f;
    for (int c = 0; c < 2; c++) {
      const float* w1 = W1 + e*30 + c*15;
      const float* w2 = W2 + e*30 + c*15;
      int jlo = tid - 14; if (jlo < 0) jlo = 0;
      int jhi = tid;      if (jhi > 14) jhi = 14;
      for (int j = jlo; j <= jhi; j++) acc += w2[j] * w1[tid - j];
    }
    sW[tid] = acc;
  } else if (tid == 29) {
    float s20 = 0.f, s21 = 0.f;
    for (int j = 0; j < 15; j++) { s20 += W2[e*30 + j]; s21 += W2[e*30 + 15 + j]; }
    sW[29] = b2[e] + s20*b1[e*2] + s21*b1[e*2 + 1];
  } else if (tid >= 32 && tid < 62) {
    sW[tid] = W1[e*30 + (tid - 32)];
  } else if (tid >= 64 && tid < 94) {
    sW[tid] = W2[e*30 + (tid - 64)];
  } else if (tid == 94 || tid == 95) {
    sW[tid] = b1[e*2 + (tid - 94)];
  }
  __syncthreads();

  // ---- boundary: clipped h~ at out-of-range positions, BOTH row edges.
  // idx in [0, 28d): [0,14d) = first edge, [14d,28d) = last edge.
  for (int idx = tid; idx < 28 * d; idx += 512) {
    int q = idx;
    int lastf = (q >= 14 * d);
    if (lastf) q -= 14 * d;
    int c  = (q >= 7 * d) ? 1 : 0;
    int u  = c ? (q - 7 * d) : q;
    int ph = u & (d - 1);
    int nbase = lastf ? (M + 7) : 0;
    const float* bp = &sxp[ph * Lp + (u >> e) + nbase];
    float h = sW[94 + c];
    #pragma unroll
    for (int k = 0; k < 15; k++) h = fmaf(sW[32 + c*15 + k], bp[k], h);
    (lastf ? hbL : hbF)[c * 7 * d + u] = h;
  }

  float W[29];
  #pragma unroll
  for (int s = 0; s < 29; s++) W[s] = sW[s];
  const float Bc = sW[29];
  __syncthreads();

  // ---- main composed conv: 4 groups of 4 chain outputs per thread
  float* lr = latent + (b * EE + e) * TT;
  #pragma unroll 1
  for (int g = 0; g < 4; g++) {
    const int vt = g * 512 + tid;            // virtual thread 0..2047
    const int ph = vt & (d - 1);
    const int m0 = (vt >> e) << 2;           // phase-local first output index

    float win[32];
    {
      const float4* wp = (const float4*)&sxp[ph * Lp + m0];
      #pragma unroll
      for (int v = 0; v < 8; v++) {
        float4 qv = wp[v];
        win[4*v] = qv.x; win[4*v+1] = qv.y; win[4*v+2] = qv.z; win[4*v+3] = qv.w;
      }
    }
    float acc[4] = {Bc, Bc, Bc, Bc};
    #pragma unroll
    for (int s = 0; s < 29; s++) {
      #pragma unroll
      for (int r = 0; r < 4; r++) acc[r] = fmaf(W[s], win[s + r], acc[r]);
    }

    // first-edge correction (<= 7 taps * 2ch per affected output)
    if (m0 <= 6) {
      #pragma unroll
      for (int r = 0; r < 4; r++) {
        int m = m0 + r;
        if (m <= 6) {
          float corr = 0.0f;
          for (int j = 0; j <= 6 - m; j++) {
            int ih = ph + (m + j) * d;
            corr = fmaf(sW[64 + j], hbF[ih], corr);
            corr = fmaf(sW[79 + j], hbF[7*d + ih], corr);
          }
          acc[r] -= corr;
        }
      }
    }
    // last-edge correction
    if (m0 + 3 >= M - 7) {
      #pragma unroll
      for (int r = 0; r < 4; r++) {
        int m = m0 + r;
        if (m >= M - 7) {
          float corr = 0.0f;
          for (int j = M + 7 - m; j < 15; j++) {
            int ih = ph + (m + j - 7 - M) * d;
            corr = fmaf(sW[64 + j], hbL[ih], corr);
            corr = fmaf(sW[79 + j], hbL[7*d + ih], corr);
          }
          acc[r] -= corr;
        }
      }
    }

    #pragma unroll
    for (int r = 0; r < 4; r++) lr[ph + (m0 + r) * d] = acc[r];
  }
}

// =====================================================================
// Kernel B: real-packed FFT (N=4096 radix-4) + moments + fc phase.
// 512 threads; native __sinf/__cosf only (no slow-path sincos).
// =====================================================================
#define NF 4096

__device__ __forceinline__ int rev4(int k) {   // base-4 digit reversal, 6 digits
  unsigned r = __brev((unsigned)k) >> 20;      // 12-bit bit reversal
  return (int)(((r & 0x555u) << 1) | ((r >> 1) & 0x555u));
}

__global__ __launch_bounds__(512) void fft_kernel(
    const float* __restrict__ latent, const float* __restrict__ fcW,
    const float* __restrict__ fcb, float* __restrict__ outP,
    float* __restrict__ outF, float* __restrict__ outA, float* __restrict__ outB0)
{
  __shared__ float re[SWZ(NF - 1) + 1];
  __shared__ float im[SWZ(NF - 1) + 1];
  __shared__ float rbuf[32];
  const int e = blockIdx.x, b = blockIdx.y, tid = threadIdx.x;
  const float2* row2 = (const float2*)(latent + (b*EE + e)*TT);
  const float2* f02  = (const float2*)(fcW + (e*2 + 0)*TT);
  const float2* f12  = (const float2*)(fcW + (e*2 + 1)*TT);

  float v0 = 0.f, v1 = 0.f;
  for (int n = tid; n < NF; n += 512) {
    float2 z = row2[n];
    re[SWZ(n)] = z.x; im[SWZ(n)] = z.y;
    float2 a0 = f02[n], a1 = f12[n];
    v0 = fmaf(z.x, a0.x, v0); v0 = fmaf(z.y, a0.y, v0);
    v1 = fmaf(z.x, a1.x, v1); v1 = fmaf(z.y, a1.y, v1);
  }
  __syncthreads();

  for (int L = NF >> 2; L >= 1; L >>= 2) {
    float wstep = -1.57079632679f / (float)L;
    for (int u = tid; u < (NF >> 2); u += 512) {
      int p = u & (L - 1);
      int base = ((u - p) << 2) + p;
      int i0 = SWZ(base), i1 = SWZ(base + L), i2 = SWZ(base + 2*L), i3 = SWZ(base + 3*L);
      float ar = re[i0], ai = im[i0];
      float br = re[i1], bi = im[i1];
      float cr = re[i2], ci = im[i2];
      float dr = re[i3], di = im[i3];
      float t0r = ar + cr, t0i = ai + ci;
      float t1r = ar - cr, t1i = ai - ci;
      float t2r = br + dr, t2i = bi + di;
      float t3r = br - dr, t3i = bi - di;
      float A0r = t0r + t2r, A0i = t0i + t2i;
      float A1r = t1r + t3i, A1i = t1i - t3r;
      float A2r = t0r - t2r, A2i = t0i - t2i;
      float A3r = t1r - t3i, A3i = t1i + t3r;
      float ang = wstep * (float)p;
      float s1 = __sinf(ang), c1 = __cosf(ang);
      float c2 = c1*c1 - s1*s1, s2 = 2.f*c1*s1;
      float c3 = c1*c2 - s1*s2, s3 = c1*s2 + s1*c2;
      re[i0] = A0r;                 im[i0] = A0i;
      re[i1] = A1r*c1 - A1i*s1;     im[i1] = A1r*s1 + A1i*c1;
      re[i2] = A2r*c2 - A2i*s2;     im[i2] = A2r*s2 + A2i*c2;
      re[i3] = A3r*c3 - A3i*s3;     im[i3] = A3r*s3 + A3i*c3;
    }
    __syncthreads();
  }

  float pacc = 0.f, facc = 0.f;
  for (int k = 1 + tid; k < NF; k += 512) {
    int jk = SWZ(rev4(k));
    int jm = SWZ(rev4(NF - k));
    float zr = re[jk], zi = im[jk];
    float yr = re[jm], yi = im[jm];
    float Er = 0.5f*(zr + yr), Ei = 0.5f*(zi - yi);
    float Dr = 0.5f*(zr - yr), Di = 0.5f*(zi + yi);
    float Or = Di, Oi = -Dr;
    float ang = -PI_F * (float)k / (float)NF;
    float s = __sinf(ang), c = __cosf(ang);
    float Xr = Er + c*Or - s*Oi;
    float Xi = Ei + c*Oi + s*Or;
    float mag = fmaf(Xr, Xr, Xi*Xi);
    pacc += mag;
    facc = fmaf(0.5f * (float)k, mag, facc);
  }
  if (tid == 0) {
    float X = re[SWZ(0)] - im[SWZ(0)];
    pacc += X*X;
    facc += 2048.0f * X*X;
  }

  #pragma unroll
  for (int off = 32; off > 0; off >>= 1) {
    pacc += __shfl_down(pacc, off);
    facc += __shfl_down(facc, off);
    v0   += __shfl_down(v0, off);
    v1   += __shfl_down(v1, off);
  }
  int wid = tid >> 6, lane = tid & 63;
  if (lane == 0) {
    rbuf[wid*4 + 0] = pacc; rbuf[wid*4 + 1] = facc;
    rbuf[wid*4 + 2] = v0;   rbuf[wid*4 + 3] = v1;
  }
  __syncthreads();
  if (tid == 0) {
    float P = 0.f, Fw = 0.f, V0 = 0.f, V1 = 0.f;
    #pragma unroll
    for (int w = 0; w < 8; w++) {
      P += rbuf[w*4]; Fw += rbuf[w*4+1]; V0 += rbuf[w*4+2]; V1 += rbuf[w*4+3];
    }
    float z0r = re[SWZ(0)], z0i = im[SWZ(0)];
    float amp  = 2.0f * sqrtf(P) / (float)TT;
    float boff = (z0r + z0i) / (float)TT;
    float vv0 = V0 + fcb[e*2 + 0];
    float vv1 = V1 + fcb[e*2 + 1];
    float ph  = atan2f(vv1, vv0) / TPI_F;
    int idx = b*EE + e;
    outP[idx]  = ph;
    outF[idx]  = Fw / P;
    outA[idx]  = amp;
    outB0[idx] = boff;
  }
}

// =====================================================================
// Kernel C: sinusoid reconstruction + fused deconv tree.
// =====================================================================
#define SST 1068
#define SL0 1056
#define SL1 1040

__global__ __launch_bounds__(256) void sig_deconv_kernel(
    const float* __restrict__ Pv, const float* __restrict__ Fv,
    const float* __restrict__ Av, const float* __restrict__ B0v,
    const float* __restrict__ dW0, const float* __restrict__ db0,
    const float* __restrict__ dW1, const float* __restrict__ db1,
    const float* __restrict__ dW2, const float* __restrict__ db2,
    float* __restrict__ sig, float* __restrict__ out)
{
  __shared__ float smem[4*SL0 + 8*SST];
  float* sl0  = smem;
  float* ssig = smem + 4*SL0;
  float* sl1  = smem + 4*SL0;   // overlays ssig after level 0

  const int tile = blockIdx.x, b = blockIdx.y;
  const int t0 = tile * TILE_C;
  const int tid = threadIdx.x;
  const float step = 2.0f / 8191.0f;

  // ---- per-channel params (uniform -> SGPRs)
  float fs[8], am[8], psh[8], bo[8];
  #pragma unroll
  for (int ch = 0; ch < EE; ch++) {
    int idx = b*EE + ch;
    fs[ch] = Fv[idx]; am[ch] = Av[idx]; psh[ch] = Pv[idx]; bo[ch] = B0v[idx];
  }

  // ---- sinusoid generation, all channels in one flattened loop
  for (int i = tid; i < SST; i += 256) {
    int t = t0 + i - 21;
    bool in = (i < 1066 && t >= 0 && t < TT);
    float arg = fmaf(step, (float)t, -1.0f);
    bool wr = (i >= 21 && i < 21 + TILE_C);
    #pragma unroll
    for (int ch = 0; ch < EE; ch++) {
      float rr = fmaf(fs[ch], arg, psh[ch]);
      rr -= rintf(rr);
      float val = in ? fmaf(am[ch], __sinf(TPI_F * rr), bo[ch]) : 0.0f;
      ssig[ch*SST + i] = val;
      if (wr) sig[(b*EE + ch)*TT + t] = val;
    }
  }
  __syncthreads();

  // ---- level 0: 8 -> 4 channels
  for (int g = 0; g < 4; g++) {
    float bg = db0[g];
    for (int u = tid; u < 263; u += 256) {
      const float4* p0 = (const float4*)(ssig + (2*g)*SST + 4*u);
      const float4* p1 = (const float4*)(ssig + (2*g+1)*SST + 4*u);
      float w0[20], w1[20];
      #pragma unroll
      for (int v = 0; v < 5; v++) {
        float4 q0 = p0[v], q1 = p1[v];
        w0[4*v]=q0.x; w0[4*v+1]=q0.y; w0[4*v+2]=q0.z; w0[4*v+3]=q0.w;
        w1[4*v]=q1.x; w1[4*v+1]=q1.y; w1[4*v+2]=q1.z; w1[4*v+3]=q1.w;
      }
      #pragma unroll
      for (int r = 0; r < 4; r++) {
        int i0 = 4*u + r;
        int t = t0 + i0 - 14;
        float a2 = bg;
        #pragma unroll
        for (int k = 0; k < KK; k++) {
          a2 = fmaf(dW0[g*30 + k],      w0[r + k], a2);
          a2 = fmaf(dW0[g*30 + 15 + k], w1[r + k], a2);
        }
        sl0[g*SL0 + i0] = (t >= 0 && t < TT) ? a2 : 0.0f;
      }
    }
  }
  if (tid < 16) sl0[(tid >> 2)*SL0 + 1052 + (tid & 3)] = 0.0f;
  __syncthreads();

  // ---- level 1: 4 -> 2 channels
  for (int g = 0; g < 2; g++) {
    float bg = db1[g];
    for (int u = tid; u < 260; u += 256) {
      const float4* p0 = (const float4*)(sl0 + (2*g)*SL0 + 4*u);
      const float4* p1 = (const float4*)(sl0 + (2*g+1)*SL0 + 4*u);
      float w0[20], w1[20];
      #pragma unroll
      for (int v = 0; v < 5; v++) {
        float4 q0 = p0[v], q1 = p1[v];
        w0[4*v]=q0.x; w0[4*v+1]=q0.y; w0[4*v+2]=q0.z; w0[4*v+3]=q0.w;
        w1[4*v]=q1.x; w1[4*v+1]=q1.y; w1[4*v+2]=q1.z; w1[4*v+3]=q1.w;
      }
      #pragma unroll
      for (int r = 0; r < 4; r++) {
        int i1 = 4*u + r;
        if (i1 < 1038) {
          int t = t0 + i1 - 7;
          float a2 = bg;
          #pragma unroll
          for (int k = 0; k < KK; k++) {
            a2 = fmaf(dW1[g*30 + k],      w0[r + k], a2);
            a2 = fmaf(dW1[g*30 + 15 + k], w1[r + k], a2);
          }
          sl1[g*SL1 + i1] = (t >= 0 && t < TT) ? a2 : 0.0f;
        }
      }
    }
  }
  __syncthreads();

  // ---- level 2: 2 -> 1 channel
  {
    float bg = db2[0];
    float* orow = out + b*TT + t0;
    int u = tid;
    const float4* p0 = (const float4*)(sl1 + 4*u);
    const float4* p1 = (const float4*)(sl1 + SL1 + 4*u);
    float w0[20], w1[20];
    #pragma unroll
    for (int v = 0; v < 5; v++) {
      float4 q0 = p0[v], q1 = p1[v];
      w0[4*v]=q0.x; w0[4*v+1]=q0.y; w0[4*v+2]=q0.z; w0[4*v+3]=q0.w;
      w1[4*v]=q1.x; w1[4*v+1]=q1.y; w1[4*v+2]=q1.z; w1[4*v+3]=q1.w;
    }
    float4 res;
    float* resf = (float*)&res;
    #pragma unroll
    for (int r = 0; r < 4; r++) {
      float a2 = bg;
      #pragma unroll
      for (int k = 0; k < KK; k++) {
        a2 = fmaf(dW2[k],      w0[r + k], a2);
        a2 = fmaf(dW2[15 + k], w1[r + k], a2);
      }
      resf[r] = a2;
    }
    ((float4*)orow)[u] = res;
  }
}

extern "C" void kernel_launch(void* const* d_in, const int* in_sizes, int n_in,
                              void* d_out, int out_size, void* d_ws, size_t ws_size,
                              hipStream_t stream) {
  const float* x   = (const float*)d_in[0];
  const float* W1  = (const float*)d_in[1];
  const float* b1  = (const float*)d_in[2];
  const float* W2  = (const float*)d_in[3];
  const float* b2  = (const float*)d_in[4];
  const float* fcW = (const float*)d_in[5];
  const float* fcb = (const float*)d_in[6];
  const float* dW0 = (const float*)d_in[7];
  const float* db0 = (const float*)d_in[8];
  const float* dW1 = (const float*)d_in[9];
  const float* db1 = (const float*)d_in[10];
  const float* dW2 = (const float*)d_in[11];
  const float* db2 = (const float*)d_in[12];

  float* o        = (float*)d_out;
  float* out_main = o + OFF_OUT;
  float* latent   = o + OFF_LAT;
  float* sig      = o + OFF_SIG;
  float* pP  = o + OFF_P;
  float* pF  = o + OFF_F;
  float* pA  = o + OFF_A;
  float* pB0 = o + OFF_B0;

  // dynamic LDS: worst case e=7 -> 128*92 + 28*128 + 96 = 15456 floats
  const size_t lds_conv = 15456 * sizeof(float);   // 61824 B < 64 KiB
  conv_stack_kernel<<<dim3(EE, BB), 512, lds_conv, stream>>>(x, W1, b1, W2, b2, latent);
  fft_kernel<<<dim3(EE, BB), 512, 0, stream>>>(latent, fcW, fcb, pP, pF, pA, pB0);
  sig_deconv_kernel<<<dim3(TT/TILE_C, BB), 256, 0, stream>>>(
      pP, pF, pA, pB0, dW0, db0, dW1, db1, dW2, db2, sig, out_main);
}